// Round 5
// baseline (223.818 us; speedup 1.0000x reference)
//
#include <hip/hip_runtime.h>

#define NN 1024
#define DD 128
#define NBLK 256

typedef __attribute__((ext_vector_type(4))) float f32x4;

// Grid barrier (256 blocks): 16 sub-counters (128B lines, 16 blocks each) -> master -> flag.
// tid0-only fences; RELAXED polling on one line; one acquire fence on exit.
// 256 blocks x 1024 threads, ~91KB LDS -> 1 block/CU, all resident => spin safe.
__device__ __forceinline__ void gridbar(unsigned* bar, unsigned ep) {
    __syncthreads();
    if (threadIdx.x == 0) {
        __threadfence();   // release: drain this block's stores toward IC
        unsigned old = __hip_atomic_fetch_add(&bar[(blockIdx.x & 15) << 5], 1u,
                                              __ATOMIC_RELAXED, __HIP_MEMORY_SCOPE_AGENT);
        if (old == (ep << 4) - 1) {                    // 16 blocks/sub-counter done
            unsigned mold = __hip_atomic_fetch_add(&bar[512], 1u,
                                                   __ATOMIC_RELAXED, __HIP_MEMORY_SCOPE_AGENT);
            if (mold == (ep << 4) - 1)                 // all 16 sub-counters done
                __hip_atomic_store(&bar[544], ep, __ATOMIC_RELAXED, __HIP_MEMORY_SCOPE_AGENT);
        }
        while (__hip_atomic_load(&bar[544], __ATOMIC_RELAXED, __HIP_MEMORY_SCOPE_AGENT) < ep)
            __builtin_amdgcn_s_sleep(4);
        __threadfence();   // acquire: invalidate stale cached lines once
    }
    __syncthreads();
}

__global__ __launch_bounds__(1024, 4) void k_fused(
    const float* __restrict__ adj, const float* __restrict__ ew,
    const float* __restrict__ nf, const float* __restrict__ We, const float* __restrict__ be,
    const float* __restrict__ Wu, const float* __restrict__ bu,
    const float* __restrict__ Wv, const float* __restrict__ bv,
    const float* __restrict__ Wg, const float* __restrict__ bg,
    const float* __restrict__ Wc1, const float* __restrict__ bc1,
    const float* __restrict__ Wc2, const float* __restrict__ bc2,
    float* __restrict__ v0, float* __restrict__ v1,
    float* __restrict__ hi, float* __restrict__ hj,
    float* __restrict__ S1, float* __restrict__ S2,
    float* __restrict__ lossAcc, unsigned* __restrict__ counter,
    unsigned* __restrict__ barCnt, float* __restrict__ outL)
{
    // Transposed per-block state: xT[dim][row] so GEMMs read one b128 broadcast per k.
    __shared__ float hT[DD][4], uT[DD][4], aggT[DD][4];     // 6KB
    __shared__ float gg[2][4][DD];                          // 4KB gate partials
    __shared__ float sred[2][4][2];
    __shared__ float wS[DD];                                // Wc2 (edge)
    __shared__ union {
        struct { float adjT[NN][4]; float pS[32][4][DD]; } g;            // 16KB + 64KB
        struct { float hiS[64][132]; float hjS[64][132]; float lred[16]; } e;  // 67.8KB
    } sm;

    int tid = threadIdx.x, bx = blockIdx.x;
    int row0 = bx * 4;
    unsigned ep = 0;

    // ---------------- Phase 0: stage adj rows (transposed) + embed + layer-0 u/v ----------------
    {
        int r = tid >> 8, k0 = (tid & 255) << 2;
        f32x4 a = *(const f32x4*)(adj + (size_t)(row0 + r) * NN + k0);
#pragma unroll
        for (int i = 0; i < 4; ++i) sm.g.adjT[k0 + i][r] = a[i];
    }
    if (tid < 512) {
        int r = tid >> 7, d = tid & 127;
        float a = be[d];
#pragma unroll
        for (int k = 0; k < 3; ++k) a = fmaf(nf[(row0 + r) * 3 + k], We[k * DD + d], a);
        hT[d][r] = a;
    }
    __syncthreads();
    if (tid < 256) {
        int half = tid >> 7, d = tid & 127;
        const float* W = half ? Wv : Wu;
        float acc[4] = {0.f, 0.f, 0.f, 0.f};
#pragma unroll 8
        for (int k = 0; k < DD; ++k) {
            f32x4 x4 = *(const f32x4*)&hT[k][0];
            float w = W[k * DD + d];
#pragma unroll
            for (int r = 0; r < 4; ++r) acc[r] = fmaf(x4[r], w, acc[r]);
        }
        if (!half) {
            float bb = bu[d];
#pragma unroll
            for (int r = 0; r < 4; ++r) uT[d][r] = acc[r] + bb;
        } else {
            float bb = bv[d];
#pragma unroll
            for (int r = 0; r < 4; ++r) v0[(size_t)(row0 + r) * DD + d] = acc[r] + bb;
        }
    }
    gridbar(barCnt, ++ep);

    // ---------------- 3 GCN layers: one barrier each ----------------
    for (int l = 0; l < 3; ++l) {
        const float* vin = (l == 1) ? v1 : v0;
        float* vout = (l == 0) ? v1 : v0;

        // agg: acc[r][d0..3] += adjT[k][r] * vin[k][d0..3], k-chunked over 32 groups
        {
            int kk = tid >> 5, dq = tid & 31;
            int d0 = dq << 2, kb = kk << 5;
            f32x4 ac0 = {0.f,0.f,0.f,0.f}, ac1 = ac0, ac2 = ac0, ac3 = ac0;
#pragma unroll 4
            for (int k = kb; k < kb + 32; ++k) {
                f32x4 a4 = *(const f32x4*)&sm.g.adjT[k][0];
                f32x4 v4 = *(const f32x4*)(vin + (size_t)k * DD + d0);
#pragma unroll
                for (int c = 0; c < 4; ++c) {
                    ac0[c] = fmaf(a4[0], v4[c], ac0[c]);
                    ac1[c] = fmaf(a4[1], v4[c], ac1[c]);
                    ac2[c] = fmaf(a4[2], v4[c], ac2[c]);
                    ac3[c] = fmaf(a4[3], v4[c], ac3[c]);
                }
            }
            *(f32x4*)&sm.g.pS[kk][0][d0] = ac0;
            *(f32x4*)&sm.g.pS[kk][1][d0] = ac1;
            *(f32x4*)&sm.g.pS[kk][2][d0] = ac2;
            *(f32x4*)&sm.g.pS[kk][3][d0] = ac3;
        }
        __syncthreads();
        if (tid < 512) {
            int r = tid >> 7, d = tid & 127;
            float s = 0.f;
#pragma unroll
            for (int c = 0; c < 32; ++c) s += sm.g.pS[c][r][d];
            aggT[d][r] = s;
        }
        __syncthreads();
        // gate GEMM halves: gg[0] = u @ WgA, gg[1] = agg @ WgB  (non-redundant W reads)
        if (tid < 256) {
            int half = tid >> 7, d = tid & 127;
            const float* W = Wg + l * (2 * DD * DD) + (half ? DD * DD : 0);
            const float (*xT)[4] = half ? aggT : uT;
            float acc[4] = {0.f, 0.f, 0.f, 0.f};
#pragma unroll 8
            for (int k = 0; k < DD; ++k) {
                f32x4 x4 = *(const f32x4*)&xT[k][0];
                float w = W[k * DD + d];
#pragma unroll
                for (int r = 0; r < 4; ++r) acc[r] = fmaf(x4[r], w, acc[r]);
            }
#pragma unroll
            for (int r = 0; r < 4; ++r) gg[half][r][d] = acc[r];
        }
        __syncthreads();
        if (tid < 512) {
            int r = tid >> 7, d = tid & 127;
            float g = 1.f / (1.f + __expf(-(gg[0][r][d] + gg[1][r][d] + bg[l * DD + d])));
            float nh = fmaf(g, aggT[d][r], hT[d][r]);
            hT[d][r] = nh > 0.f ? nh : 0.f;
        }
        __syncthreads();
        // next-layer u/v GEMM, or classifier head at l==2
        if (tid < 256) {
            int half = tid >> 7, d = tid & 127;
            const float* W2 = (l < 2) ? ((half ? Wv : Wu) + (l + 1) * DD * DD)
                                      : (Wc1 + (half ? DD * DD : 0));
            float acc[4] = {0.f, 0.f, 0.f, 0.f};
#pragma unroll 8
            for (int k = 0; k < DD; ++k) {
                f32x4 x4 = *(const f32x4*)&hT[k][0];
                float w = W2[k * DD + d];
#pragma unroll
                for (int r = 0; r < 4; ++r) acc[r] = fmaf(x4[r], w, acc[r]);
            }
            if (l < 2) {
                if (!half) {
                    float bb = bu[(l + 1) * DD + d];
#pragma unroll
                    for (int r = 0; r < 4; ++r) uT[d][r] = acc[r] + bb;
                } else {
                    float bb = bv[(l + 1) * DD + d];
#pragma unroll
                    for (int r = 0; r < 4; ++r) vout[(size_t)(row0 + r) * DD + d] = acc[r] + bb;
                }
            } else {
                float bcv = half ? 0.f : bc1[d];
                float* out2 = half ? hj : hi;
                float wv = Wc2[d];
                int w2 = (tid >> 6) & 1;
#pragma unroll
                for (int r = 0; r < 4; ++r) {
                    float val = acc[r] + bcv;
                    out2[(size_t)(row0 + r) * DD + d] = val;
                    float p = val * wv;
#pragma unroll
                    for (int off = 32; off; off >>= 1) p += __shfl_down(p, off);
                    if ((tid & 63) == 0) sred[half][r][w2] = p;
                }
            }
        }
        if (l == 2) {
            __syncthreads();
            if (tid < 4) S1[row0 + tid] = sred[0][tid][0] + sred[0][tid][1];
            else if (tid < 8) S2[row0 + tid - 4] = sred[1][tid - 4][0] + sred[1][tid - 4][1];
        }
        gridbar(barCnt, ++ep);
    }

    // ---------------- edge classifier: one 64x64 tile per block (256 tiles) + loss ----------------
    {
        int i0 = (bx >> 4) << 6, j0 = (bx & 15) << 6;
        if (tid < 128) wS[tid] = Wc2[tid];
        for (int e2 = tid; e2 < 2048; e2 += 1024) {
            int r = e2 >> 5, c = (e2 & 31) << 2;
            *(f32x4*)&sm.e.hiS[r][c] = *(const f32x4*)(hi + (size_t)(i0 + r) * DD + c);
            *(f32x4*)&sm.e.hjS[r][c] = *(const f32x4*)(hj + (size_t)(j0 + r) * DD + c);
        }
        __syncthreads();
        int ty = tid >> 5, tx = tid & 31;          // 2x2 outputs per thread
        int ia = ty << 1, ja = tx << 1;
        float a00 = 0.f, a01 = 0.f, a10 = 0.f, a11 = 0.f;
#pragma unroll 4
        for (int hh = 0; hh < DD; hh += 4) {
            f32x4 x0 = *(const f32x4*)&sm.e.hiS[ia][hh];
            f32x4 x1 = *(const f32x4*)&sm.e.hiS[ia + 1][hh];
            f32x4 y0 = *(const f32x4*)&sm.e.hjS[ja][hh];
            f32x4 y1 = *(const f32x4*)&sm.e.hjS[ja + 1][hh];
            f32x4 w4 = *(const f32x4*)&wS[hh];
#pragma unroll
            for (int q = 0; q < 4; ++q) {
                a00 = fmaf(fabsf(x0[q] + y0[q]), w4[q], a00);
                a01 = fmaf(fabsf(x0[q] + y1[q]), w4[q], a01);
                a10 = fmaf(fabsf(x1[q] + y0[q]), w4[q], a10);
                a11 = fmaf(fabsf(x1[q] + y1[q]), w4[q], a11);
            }
        }
        float bcv = bc2[0];
        int i = i0 + ia, j = j0 + ja;
        float s1a = S1[i], s1b = S1[i + 1];
        float2 s2 = *(const float2*)(S2 + j);
        float lg00 = fmaf(0.5f, a00 + s1a + s2.x, bcv);
        float lg01 = fmaf(0.5f, a01 + s1a + s2.y, bcv);
        float lg10 = fmaf(0.5f, a10 + s1b + s2.x, bcv);
        float lg11 = fmaf(0.5f, a11 + s1b + s2.y, bcv);
        size_t o0 = (size_t)i * NN + j, o1 = o0 + NN;
        float2 w0; w0.x = lg00; w0.y = lg01;
        float2 w1; w1.x = lg10; w1.y = lg11;
        *(float2*)(outL + o0) = w0;
        *(float2*)(outL + o1) = w1;
        float2 aa0 = *(const float2*)(adj + o0);
        float2 aa1 = *(const float2*)(adj + o1);
        float2 ee0 = *(const float2*)(ew + o0);
        float2 ee1 = *(const float2*)(ew + o1);
        float t0 = fmaf(lg00, aa0.x, -ee0.x);
        float t1 = fmaf(lg01, aa0.y, -ee0.y);
        float t2 = fmaf(lg10, aa1.x, -ee1.x);
        float t3 = fmaf(lg11, aa1.y, -ee1.y);
        float ls = fmaf(t0, t0, fmaf(t1, t1, fmaf(t2, t2, t3 * t3)));
#pragma unroll
        for (int off = 32; off; off >>= 1) ls += __shfl_down(ls, off);
        if ((tid & 63) == 0) sm.e.lred[tid >> 6] = ls;
        __syncthreads();
        if (tid == 0) {
            float bls = 0.f;
#pragma unroll
            for (int w = 0; w < 16; ++w) bls += sm.e.lred[w];
            atomicAdd(lossAcc, bls);
            __threadfence();
            unsigned old = atomicAdd(counter, 1u);
            if (old == NBLK - 1u) {
                __threadfence();
                outL[(size_t)NN * NN] = (*(volatile float*)lossAcc) * (1.f / (1024.f * 1024.f));
            }
        }
    }
}

extern "C" void kernel_launch(void* const* d_in, const int* in_sizes, int n_in,
                              void* d_out, int out_size, void* d_ws, size_t ws_size,
                              hipStream_t stream)
{
    const float* nf  = (const float*)d_in[0];
    const float* adj = (const float*)d_in[1];
    const float* ew  = (const float*)d_in[2];
    const float* We  = (const float*)d_in[3];
    const float* be  = (const float*)d_in[4];
    const float* Wu  = (const float*)d_in[5];
    const float* bu  = (const float*)d_in[6];
    const float* Wv  = (const float*)d_in[7];
    const float* bv  = (const float*)d_in[8];
    const float* Wg  = (const float*)d_in[9];
    const float* bg  = (const float*)d_in[10];
    const float* Wc1 = (const float*)d_in[11];
    const float* bc1 = (const float*)d_in[12];
    const float* Wc2 = (const float*)d_in[13];
    const float* bc2 = (const float*)d_in[14];

    float* ws = (float*)d_ws;
    float* v0  = ws;                                 // 131072
    float* v1  = ws + 131072;                        // 131072
    float* hi  = ws + 262144;                        // 131072
    float* hj  = ws + 393216;                        // 131072
    float* S1  = ws + 524288;                        // 1024
    float* S2  = ws + 525312;                        // 1024
    float* lossAcc = ws + 526336;                    // 1
    unsigned* counter = (unsigned*)(ws + 526337);    // 1
    unsigned* barCnt = (unsigned*)(ws + 526368);     // 545 uints (sub/master/flag)

    // zero lossAcc + counter + barrier state (capture-legal)
    hipMemsetAsync((void*)lossAcc, 0, 2560, stream);
    k_fused<<<NBLK, 1024, 0, stream>>>(adj, ew, nf, We, be, Wu, bu, Wv, bv, Wg, bg,
                                       Wc1, bc1, Wc2, bc2, v0, v1, hi, hj, S1, S2,
                                       lossAcc, counter, barCnt, (float*)d_out);
}

// Round 7
// 212.899 us; speedup vs baseline: 1.0513x; 1.0513x over previous
//
#include <hip/hip_runtime.h>

#define NN 1024
#define DD 128
#define NBLK 256

typedef __attribute__((ext_vector_type(4))) float f32x4;

// Grid barrier (256 blocks): 16 sub-counters (128B lines, 16 blocks each) -> master -> flag.
// tid0-only fences; RELAXED polling on one line (no per-poll invalidate); one acquire
// fence on exit. PROVEN protocol (rounds 2 & 4 passed on HW at 256 blocks).
// 256 blocks x 1024 threads, ~91KB LDS -> 1 block/CU, all resident => spin safe.
__device__ __forceinline__ void gridbar(unsigned* bar, unsigned ep) {
    __syncthreads();
    if (threadIdx.x == 0) {
        __threadfence();   // release: drain this block's stores toward IC
        unsigned old = __hip_atomic_fetch_add(&bar[(blockIdx.x & 15) << 5], 1u,
                                              __ATOMIC_RELAXED, __HIP_MEMORY_SCOPE_AGENT);
        if (old == (ep << 4) - 1) {                    // 16 blocks/sub-counter done
            unsigned mold = __hip_atomic_fetch_add(&bar[512], 1u,
                                                   __ATOMIC_RELAXED, __HIP_MEMORY_SCOPE_AGENT);
            if (mold == (ep << 4) - 1)                 // all 16 sub-counters done
                __hip_atomic_store(&bar[544], ep, __ATOMIC_RELAXED, __HIP_MEMORY_SCOPE_AGENT);
        }
        while (__hip_atomic_load(&bar[544], __ATOMIC_RELAXED, __HIP_MEMORY_SCOPE_AGENT) < ep)
            __builtin_amdgcn_s_sleep(4);
        __threadfence();   // acquire: invalidate stale cached lines once
    }
    __syncthreads();
}

__global__ __launch_bounds__(1024, 4) void k_fused(
    const float* __restrict__ adj, const float* __restrict__ ew,
    const float* __restrict__ nf, const float* __restrict__ We, const float* __restrict__ be,
    const float* __restrict__ Wu, const float* __restrict__ bu,
    const float* __restrict__ Wv, const float* __restrict__ bv,
    const float* __restrict__ Wg, const float* __restrict__ bg,
    const float* __restrict__ Wc1, const float* __restrict__ bc1,
    const float* __restrict__ Wc2, const float* __restrict__ bc2,
    float* __restrict__ vA, float* __restrict__ vB, float* __restrict__ vC,
    float* __restrict__ hi, float* __restrict__ hj,
    float* __restrict__ S1, float* __restrict__ S2,
    float* __restrict__ lossAcc, unsigned* __restrict__ counter,
    unsigned* __restrict__ barCnt, float* __restrict__ outL)
{
    // Row-major per-block state [4][DD]: d-consecutive lanes => conflict-free LDS.
    __shared__ float hS[4][DD], uS[4][DD], aggS[4][DD];     // 6KB
    __shared__ float gg[2][4][DD];                          // 4KB
    __shared__ float sred[2][4][2];
    __shared__ float wS[DD];
    __shared__ union {
        struct { float adjS[4][NN]; float pS[32][4][DD]; } g;              // 80KB
        struct { float hiS[64][132]; float hjS[64][132]; float lred[16]; } e;  // 67.6KB
    } sm;

    int tid = threadIdx.x, bx = blockIdx.x;
    int row0 = bx * 4;
    int halfq = tid >> 9, rq = (tid >> 7) & 3, d = tid & 127;   // GEMM: 1 output/thread
    unsigned ep = 0;

    // ---------------- Phase 0: stage adj rows + embed + layer-0 u/v ----------------
    {
        int r = tid >> 8, k0 = (tid & 255) << 2;
        *(f32x4*)&sm.g.adjS[r][k0] = *(const f32x4*)(adj + (size_t)(row0 + r) * NN + k0);
    }
    if (tid < 512) {
        int r = tid >> 7;
        float a = be[d];
#pragma unroll
        for (int k = 0; k < 3; ++k) a = fmaf(nf[(row0 + r) * 3 + k], We[k * DD + d], a);
        hS[r][d] = a;
    }
    __syncthreads();
    {
        const float* W = halfq ? Wv : Wu;
        float acc = 0.f;
#pragma unroll 4
        for (int k = 0; k < DD; k += 4) {
            f32x4 x4 = *(const f32x4*)&hS[rq][k];   // wave-uniform broadcast (free)
            acc = fmaf(x4[0], W[(k + 0) * DD + d], acc);
            acc = fmaf(x4[1], W[(k + 1) * DD + d], acc);
            acc = fmaf(x4[2], W[(k + 2) * DD + d], acc);
            acc = fmaf(x4[3], W[(k + 3) * DD + d], acc);
        }
        if (!halfq) uS[rq][d] = acc + bu[d];
        else        vA[(size_t)(row0 + rq) * DD + d] = acc + bv[d];
    }
    gridbar(barCnt, ++ep);

    // ---------------- 3 GCN layers: one barrier each ----------------
    for (int l = 0; l < 3; ++l) {
        const float* vin = (l == 0) ? vA : (l == 1) ? vB : vC;
        float* vout = (l == 0) ? vB : vC;                      // unused at l==2

        // agg partials: 32 k-chunks x 32 d-quads; 16 fp32 acc regs per thread
        {
            int kk = tid >> 5, dq = tid & 31;
            int d0 = dq << 2, kb = kk << 5;
            f32x4 ac0 = {0.f,0.f,0.f,0.f}, ac1 = ac0, ac2 = ac0, ac3 = ac0;
#pragma unroll 2
            for (int ku = 0; ku < 32; ku += 4) {
                f32x4 a0 = *(const f32x4*)&sm.g.adjS[0][kb + ku];
                f32x4 a1 = *(const f32x4*)&sm.g.adjS[1][kb + ku];
                f32x4 a2 = *(const f32x4*)&sm.g.adjS[2][kb + ku];
                f32x4 a3 = *(const f32x4*)&sm.g.adjS[3][kb + ku];
#pragma unroll
                for (int j = 0; j < 4; ++j) {
                    f32x4 v4 = *(const f32x4*)(vin + (size_t)(kb + ku + j) * DD + d0);
#pragma unroll
                    for (int c = 0; c < 4; ++c) {
                        ac0[c] = fmaf(a0[j], v4[c], ac0[c]);
                        ac1[c] = fmaf(a1[j], v4[c], ac1[c]);
                        ac2[c] = fmaf(a2[j], v4[c], ac2[c]);
                        ac3[c] = fmaf(a3[j], v4[c], ac3[c]);
                    }
                }
            }
            *(f32x4*)&sm.g.pS[kk][0][d0] = ac0;
            *(f32x4*)&sm.g.pS[kk][1][d0] = ac1;
            *(f32x4*)&sm.g.pS[kk][2][d0] = ac2;
            *(f32x4*)&sm.g.pS[kk][3][d0] = ac3;
        }
        __syncthreads();
        if (tid < 512) {
            int r = tid >> 7;
            float s = 0.f;
#pragma unroll
            for (int c = 0; c < 32; ++c) s += sm.g.pS[c][r][d];
            aggS[r][d] = s;
        }
        __syncthreads();
        // gate halves: gg[0] = u @ WgA, gg[1] = agg @ WgB  (1024 threads, 1 output each)
        {
            const float* W = Wg + l * (2 * DD * DD) + (halfq ? DD * DD : 0);
            const float (*xS)[DD] = halfq ? aggS : uS;
            float acc = 0.f;
#pragma unroll 4
            for (int k = 0; k < DD; k += 4) {
                f32x4 x4 = *(const f32x4*)&xS[rq][k];
                acc = fmaf(x4[0], W[(k + 0) * DD + d], acc);
                acc = fmaf(x4[1], W[(k + 1) * DD + d], acc);
                acc = fmaf(x4[2], W[(k + 2) * DD + d], acc);
                acc = fmaf(x4[3], W[(k + 3) * DD + d], acc);
            }
            gg[halfq][rq][d] = acc;
        }
        __syncthreads();
        if (tid < 512) {
            int r = tid >> 7;
            float g = 1.f / (1.f + __expf(-(gg[0][r][d] + gg[1][r][d] + bg[l * DD + d])));
            float nh = fmaf(g, aggS[r][d], hS[r][d]);
            hS[r][d] = nh > 0.f ? nh : 0.f;
        }
        __syncthreads();
        // next-layer u/v GEMM, or classifier head at l==2
        {
            const float* W2 = (l < 2) ? ((halfq ? Wv : Wu) + (l + 1) * DD * DD)
                                      : (Wc1 + (halfq ? DD * DD : 0));
            float acc = 0.f;
#pragma unroll 4
            for (int k = 0; k < DD; k += 4) {
                f32x4 x4 = *(const f32x4*)&hS[rq][k];
                acc = fmaf(x4[0], W2[(k + 0) * DD + d], acc);
                acc = fmaf(x4[1], W2[(k + 1) * DD + d], acc);
                acc = fmaf(x4[2], W2[(k + 2) * DD + d], acc);
                acc = fmaf(x4[3], W2[(k + 3) * DD + d], acc);
            }
            if (l < 2) {
                if (!halfq) uS[rq][d] = acc + bu[(l + 1) * DD + d];
                else        vout[(size_t)(row0 + rq) * DD + d] = acc + bv[(l + 1) * DD + d];
            } else {
                float val = acc + (halfq ? 0.f : bc1[d]);
                (halfq ? hj : hi)[(size_t)(row0 + rq) * DD + d] = val;
                float p = val * Wc2[d];
#pragma unroll
                for (int off = 32; off; off >>= 1) p += __shfl_down(p, off);
                if ((tid & 63) == 0) sred[halfq][rq][(tid >> 6) & 1] = p;
            }
        }
        if (l == 2) {
            __syncthreads();
            if (tid < 4) S1[row0 + tid] = sred[0][tid][0] + sred[0][tid][1];
            else if (tid < 8) S2[row0 + tid - 4] = sred[1][tid - 4][0] + sred[1][tid - 4][1];
        }
        gridbar(barCnt, ++ep);
    }

    // ---------------- edge classifier: one 64x64 tile per block + loss ----------------
    {
        int i0 = (bx >> 4) << 6, j0 = (bx & 15) << 6;
        if (tid < 128) wS[tid] = Wc2[tid];
        for (int e2 = tid; e2 < 2048; e2 += 1024) {
            int r = e2 >> 5, c = (e2 & 31) << 2;
            *(f32x4*)&sm.e.hiS[r][c] = *(const f32x4*)(hi + (size_t)(i0 + r) * DD + c);
            *(f32x4*)&sm.e.hjS[r][c] = *(const f32x4*)(hj + (size_t)(j0 + r) * DD + c);
        }
        __syncthreads();
        // strided 2x2 tile: rows (ty, ty+32) x cols (tx, tx+32).
        // y-reads: 32 distinct rows x 2-lane broadcast; 128 dwords uniform 4/bank => min rounds.
        int ty = tid >> 5, tx = tid & 31;
        float a00 = 0.f, a01 = 0.f, a10 = 0.f, a11 = 0.f;
#pragma unroll 4
        for (int hh = 0; hh < DD; hh += 4) {
            f32x4 x0 = *(const f32x4*)&sm.e.hiS[ty][hh];
            f32x4 x1 = *(const f32x4*)&sm.e.hiS[ty + 32][hh];
            f32x4 y0 = *(const f32x4*)&sm.e.hjS[tx][hh];
            f32x4 y1 = *(const f32x4*)&sm.e.hjS[tx + 32][hh];
            f32x4 w4 = *(const f32x4*)&wS[hh];
#pragma unroll
            for (int q = 0; q < 4; ++q) {
                a00 = fmaf(fabsf(x0[q] + y0[q]), w4[q], a00);
                a01 = fmaf(fabsf(x0[q] + y1[q]), w4[q], a01);
                a10 = fmaf(fabsf(x1[q] + y0[q]), w4[q], a10);
                a11 = fmaf(fabsf(x1[q] + y1[q]), w4[q], a11);
            }
        }
        float bcv = bc2[0];
        int ia = i0 + ty, ib = ia + 32, ja = j0 + tx, jb = ja + 32;
        float s1a = S1[ia], s1b = S1[ib];
        float s2a = S2[ja], s2b = S2[jb];
        float lg00 = fmaf(0.5f, a00 + s1a + s2a, bcv);
        float lg01 = fmaf(0.5f, a01 + s1a + s2b, bcv);
        float lg10 = fmaf(0.5f, a10 + s1b + s2a, bcv);
        float lg11 = fmaf(0.5f, a11 + s1b + s2b, bcv);
        size_t o00 = (size_t)ia * NN + ja, o01 = (size_t)ia * NN + jb;
        size_t o10 = (size_t)ib * NN + ja, o11 = (size_t)ib * NN + jb;
        outL[o00] = lg00; outL[o01] = lg01; outL[o10] = lg10; outL[o11] = lg11;
        float t0 = fmaf(lg00, adj[o00], -ew[o00]);
        float t1 = fmaf(lg01, adj[o01], -ew[o01]);
        float t2 = fmaf(lg10, adj[o10], -ew[o10]);
        float t3 = fmaf(lg11, adj[o11], -ew[o11]);
        float ls = fmaf(t0, t0, fmaf(t1, t1, fmaf(t2, t2, t3 * t3)));
#pragma unroll
        for (int off = 32; off; off >>= 1) ls += __shfl_down(ls, off);
        if ((tid & 63) == 0) sm.e.lred[tid >> 6] = ls;
        __syncthreads();
        if (tid == 0) {
            float bls = 0.f;
#pragma unroll
            for (int w = 0; w < 16; ++w) bls += sm.e.lred[w];
            atomicAdd(lossAcc, bls);
            __threadfence();
            unsigned old = atomicAdd(counter, 1u);
            if (old == NBLK - 1u) {
                __threadfence();
                outL[(size_t)NN * NN] = (*(volatile float*)lossAcc) * (1.f / (1024.f * 1024.f));
            }
        }
    }
}

extern "C" void kernel_launch(void* const* d_in, const int* in_sizes, int n_in,
                              void* d_out, int out_size, void* d_ws, size_t ws_size,
                              hipStream_t stream)
{
    const float* nf  = (const float*)d_in[0];
    const float* adj = (const float*)d_in[1];
    const float* ew  = (const float*)d_in[2];
    const float* We  = (const float*)d_in[3];
    const float* be  = (const float*)d_in[4];
    const float* Wu  = (const float*)d_in[5];
    const float* bu  = (const float*)d_in[6];
    const float* Wv  = (const float*)d_in[7];
    const float* bv  = (const float*)d_in[8];
    const float* Wg  = (const float*)d_in[9];
    const float* bg  = (const float*)d_in[10];
    const float* Wc1 = (const float*)d_in[11];
    const float* bc1 = (const float*)d_in[12];
    const float* Wc2 = (const float*)d_in[13];
    const float* bc2 = (const float*)d_in[14];

    float* ws = (float*)d_ws;
    float* vA  = ws;                                 // 131072  (write-once: phase0)
    float* vB  = ws + 131072;                        // 131072  (write-once: layer0)
    float* vC  = ws + 262144;                        // 131072  (write-once: layer1)
    float* hi  = ws + 393216;                        // 131072  (write-once: layer2)
    float* hj  = ws + 524288;                        // 131072  (write-once: layer2)
    float* S1  = ws + 655360;                        // 1024
    float* S2  = ws + 656384;                        // 1024
    float* lossAcc = ws + 657408;                    // 1
    unsigned* counter = (unsigned*)(ws + 657409);    // 1
    unsigned* barCnt = (unsigned*)(ws + 657440);     // 545 uints (sub/master/flag)

    // zero lossAcc + counter + barrier state (capture-legal)
    hipMemsetAsync((void*)lossAcc, 0, 2560, stream);
    k_fused<<<NBLK, 1024, 0, stream>>>(adj, ew, nf, We, be, Wu, bu, Wv, bv, Wg, bg,
                                       Wc1, bc1, Wc2, bc2, vA, vB, vC, hi, hj, S1, S2,
                                       lossAcc, counter, barCnt, (float*)d_out);
}